// Round 7
// baseline (2995.018 us; speedup 1.0000x reference)
//
#include <hip/hip_runtime.h>

#define B_    4
#define N_    8192
#define CIN   128
#define COUT  256
#define M_    2048
#define K_    16
#define DM    64
#define MAXNN 64
#define CAP   128
#define R2    0.01f
#define EXT   0.1f

typedef float v2f __attribute__((ext_vector_type(2)));

// Exact-rounded squared distance matching numpy's op order: (dx*dx + dy*dy) + dz*dz
__device__ __forceinline__ float d2_exact(float ax, float ay, float az,
                                          float bx, float by, float bz) {
    float dx = ax - bx, dy = ay - by, dz = az - bz;
    return __fadd_rn(__fadd_rn(__fmul_rn(dx, dx), __fmul_rn(dy, dy)), __fmul_rn(dz, dz));
}

// Packed distance update for one float2 pair of points, exact numpy rounding:
// d2 = ((dx*dx + dy*dy) + dz*dz). Subtraction done as p + (-c) with a pre-negated
// center (exact in IEEE), so no neg_lo/neg_hi modifiers are needed. Plain VALU
// (no DPP) => no wait-state hazards inside the block.
#define PAIR_UPD(JJ)                                                         \
    { v2f d2v, t0v, t1v;                                                     \
      asm("v_pk_add_f32 %0, %3, %6\n\t"                                      \
          "v_pk_add_f32 %1, %4, %7\n\t"                                      \
          "v_pk_add_f32 %2, %5, %8\n\t"                                      \
          "v_pk_mul_f32 %0, %0, %0\n\t"                                      \
          "v_pk_mul_f32 %1, %1, %1\n\t"                                      \
          "v_pk_mul_f32 %2, %2, %2\n\t"                                      \
          "v_pk_add_f32 %0, %0, %1\n\t"                                      \
          "v_pk_add_f32 %0, %0, %2"                                          \
          : "=&v"(d2v), "=&v"(t0v), "=&v"(t1v)                               \
          : "v"(px[JJ]), "v"(py[JJ]), "v"(pz[JJ]),                           \
            "v"(ncx2), "v"(ncy2), "v"(ncz2));                                \
      mnd[2*(JJ)]   = fminf(mnd[2*(JJ)],   d2v.x);                           \
      mnd[2*(JJ)+1] = fminf(mnd[2*(JJ)+1], d2v.y);                           \
      bv0 = fmaxf(bv0, mnd[2*(JJ)]);                                         \
      bv1 = fmaxf(bv1, mnd[2*(JJ)+1]); }

// Value max-reduce step via builtin DPP (compiler inserts the required
// VALU->DPP wait states — hand-written asm DPP chains here are a known hazard).
#define VMAX_DPP(CTRL)                                                        \
    red = fmaxf(red, __uint_as_float((unsigned)__builtin_amdgcn_update_dpp(   \
                  0, (int)__float_as_uint(red), CTRL, 0xF, 0xF, true)));

// ---------------- K1 (merged): blocks 0..3 = FPS; blocks >=4 = pre-MLP ----------------
// FPS: 512 threads (8 waves), 16 pts/lane as 8 x float2 in asm-pinned VGPRs.
// Hot loop: packed-f32 distance update + min/max only (no index tracking).
// Wave value-reduce: 6 DPP v_max steps -> lane63 -> LDS atomicMax on float bits
// (monotone, d2 >= 0). Barrier A. Lanes whose local max equals the global max scan
// their 16 mind values for the first match and atomicMin u64 keys (n<<32|coord_bits)
// into 3 slots: min over n == numpy first-index tie-break; winning coords ride along.
// Barrier B, everyone reads idx+center from LDS (no global center load in the chain).
__global__ __launch_bounds__(512) void fps_pre_kernel(const float* __restrict__ pos,
                                                      int* __restrict__ idx_out,
                                                      float* __restrict__ out_pos,
                                                      const float* __restrict__ x,
                                                      const float* __restrict__ Wp,
                                                      const float* __restrict__ bvec,
                                                      float* __restrict__ xpre) {
    __shared__ union {
        struct {
            unsigned slotV[2];
            unsigned long long slotC[2][3];
        } f;
        struct { float Ws[CIN * DM]; float xs[32][CIN]; } p;   // 48 KB
    } sh;

    const int t = threadIdx.x;

    if (blockIdx.x >= 4) {
        // ---------------- pre-MLP branch: 32 rows per block ----------------
        const size_t rowBase = (size_t)(blockIdx.x - 4) * 32;
        for (int i = t; i < CIN * DM; i += 512) sh.p.Ws[i] = Wp[i];
        for (int i = t; i < 32 * CIN; i += 512) {
            int r = i >> 7, c = i & 127;
            sh.p.xs[r][c] = x[(rowBase + r) * CIN + c];
        }
        __syncthreads();
        const int col = t & 63, r0 = t >> 6;   // r0 in [0,8)
        float acc[4];
        float bias = bvec[col];
#pragma unroll
        for (int rr = 0; rr < 4; rr++) acc[rr] = bias;
        for (int c = 0; c < CIN; c++) {
            float w = sh.p.Ws[c * DM + col];
#pragma unroll
            for (int rr = 0; rr < 4; rr++) acc[rr] = fmaf(sh.p.xs[r0 + 8 * rr][c], w, acc[rr]);
        }
#pragma unroll
        for (int rr = 0; rr < 4; rr++) xpre[(rowBase + r0 + 8 * rr) * DM + col] = acc[rr];
        return;
    }

    // ---------------- FPS branch ----------------
    const int b = blockIdx.x;
    const float* pb = pos + (size_t)b * N_ * 3;

    v2f px[8], py[8], pz[8];
    float mnd[16];
#pragma unroll
    for (int jj = 0; jj < 8; jj++) {
        int n0 = t + (2 * jj) * 512, n1 = n0 + 512;
        px[jj] = (v2f){pb[n0 * 3 + 0], pb[n1 * 3 + 0]};
        py[jj] = (v2f){pb[n0 * 3 + 1], pb[n1 * 3 + 1]};
        pz[jj] = (v2f){pb[n0 * 3 + 2], pb[n1 * 3 + 2]};
        mnd[2 * jj] = 1e30f; mnd[2 * jj + 1] = 1e30f;
    }
    float cx = pb[0], cy = pb[1], cz = pb[2];
    if (t == 0) {
        sh.f.slotV[0] = 0u; sh.f.slotV[1] = 0u;
#pragma unroll
        for (int q = 0; q < 3; q++) {
            sh.f.slotC[0][q] = ~0ull; sh.f.slotC[1][q] = ~0ull;
        }
        idx_out[b * M_ + 0] = 0;
        float* op = out_pos + ((size_t)(b * M_ + 0)) * 3;
        op[0] = cx; op[1] = cy; op[2] = cz;
    }
    __syncthreads();

    for (int m = 1; m < M_; m++) {
        // exact sign-flip; p + (-c) is bit-identical to p - c
        const float ncx = -cx, ncy = -cy, ncz = -cz;
        const v2f ncx2 = (v2f){ncx, ncx}, ncy2 = (v2f){ncy, ncy}, ncz2 = (v2f){ncz, ncz};
        float bv0 = -1.0f, bv1 = -1.0f;
        PAIR_UPD(0) PAIR_UPD(1) PAIR_UPD(2) PAIR_UPD(3)
        PAIR_UPD(4) PAIR_UPD(5) PAIR_UPD(6) PAIR_UPD(7)
        const float lanemax = fmaxf(bv0, bv1);

        // wave64 value max-reduce; lane63 holds the wave max afterwards
        float red = lanemax;
        VMAX_DPP(0x111)  // row_shr:1
        VMAX_DPP(0x112)  // row_shr:2
        VMAX_DPP(0x114)  // row_shr:4
        VMAX_DPP(0x118)  // row_shr:8
        VMAX_DPP(0x142)  // row_bcast:15
        VMAX_DPP(0x143)  // row_bcast:31

        const int buf = m & 1;
        if ((t & 63) == 63) {
            atomicMax(&sh.f.slotV[buf], __float_as_uint(red));   // d2 >= 0: bits monotone
        }
        __syncthreads();   // barrier A

        const unsigned gmb = sh.f.slotV[buf];
        // reset the other-parity slots for iteration m+1 (ordered by barrier B)
        if (t == 0) {
            sh.f.slotV[buf ^ 1] = 0u;
            sh.f.slotC[buf ^ 1][0] = ~0ull;
            sh.f.slotC[buf ^ 1][1] = ~0ull;
            sh.f.slotC[buf ^ 1][2] = ~0ull;
        }
        const float gmaxf = __uint_as_float(gmb);
        if (lanemax == gmaxf) {
            // first (smallest-j) matching point of this lane; j ascending == n ascending
            unsigned nb = 0xFFFFFFFFu;
            float fx = 0.f, fy = 0.f, fz = 0.f;
#pragma unroll
            for (int jj = 0; jj < 8; jj++) {
                if (mnd[2 * jj] == gmaxf && nb == 0xFFFFFFFFu) {
                    nb = (unsigned)(t + (2 * jj) * 512);
                    fx = px[jj].x; fy = py[jj].x; fz = pz[jj].x;
                }
                if (mnd[2 * jj + 1] == gmaxf && nb == 0xFFFFFFFFu) {
                    nb = (unsigned)(t + (2 * jj + 1) * 512);
                    fx = px[jj].y; fy = py[jj].y; fz = pz[jj].y;
                }
            }
            atomicMin(&sh.f.slotC[buf][0], ((unsigned long long)nb << 32) | (unsigned long long)__float_as_uint(fx));
            atomicMin(&sh.f.slotC[buf][1], ((unsigned long long)nb << 32) | (unsigned long long)__float_as_uint(fy));
            atomicMin(&sh.f.slotC[buf][2], ((unsigned long long)nb << 32) | (unsigned long long)__float_as_uint(fz));
        }
        __syncthreads();   // barrier B

        const unsigned long long kx = sh.f.slotC[buf][0];
        const unsigned long long ky = sh.f.slotC[buf][1];
        const unsigned long long kz = sh.f.slotC[buf][2];
        const unsigned widx = (unsigned)(kx >> 32);
        cx = __uint_as_float((unsigned)kx);
        cy = __uint_as_float((unsigned)ky);
        cz = __uint_as_float((unsigned)kz);
        if (t == 0) {
            idx_out[b * M_ + m] = (int)widx;
            float* op = out_pos + ((size_t)(b * M_ + m)) * 3;
            op[0] = cx; op[1] = cy; op[2] = cz;
        }
    }
}

// ---------------- K3: fused neighbor search + KPConv + post + shortcut ----------------
__global__ __launch_bounds__(256) void conv_kernel(const float* __restrict__ pos,
                                                   const float* __restrict__ x,
                                                   const float* __restrict__ xpre,
                                                   const int* __restrict__ idxs,
                                                   const float* __restrict__ kp_pos,
                                                   const float* __restrict__ kp_W,
                                                   const float* __restrict__ W_post,
                                                   const float* __restrict__ b_post,
                                                   const float* __restrict__ W_sc,
                                                   const float* __restrict__ b_sc,
                                                   float* __restrict__ out_feat) {
    const int blk = blockIdx.x;
    const int b = blk / M_;
    const int m = blk % M_;
    const int t = threadIdx.x;

    __shared__ int   nIdx[CAP];
    __shared__ float nD2[CAP];
    __shared__ int   cntS;
    __shared__ float infl[MAXNN][K_];   // 4 KB
    __shared__ float xj[MAXNN][DM];     // 16 KB
    __shared__ float sS[K_ * DM];       // 4 KB
    __shared__ float featP[4][DM];      // 1 KB
    __shared__ float xg[CIN];           // 0.5 KB

    const float* pb = pos + (size_t)b * N_ * 3;
    const int ctr = idxs[b * M_ + m];
    const float cx = pb[ctr * 3 + 0], cy = pb[ctr * 3 + 1], cz = pb[ctr * 3 + 2];

    if (t == 0) cntS = 0;
    __syncthreads();

    // neighbor scan over all N points
    for (int j = 0; j < N_ / 256; j++) {
        int n = j * 256 + t;
        float x0 = pb[n * 3 + 0], y0 = pb[n * 3 + 1], z0 = pb[n * 3 + 2];
        float d = d2_exact(x0, y0, z0, cx, cy, cz);
        if (d <= R2) {
            int p = atomicAdd(&cntS, 1);
            if (p < CAP) { nIdx[p] = n; nD2[p] = d; }
        }
    }
    __syncthreads();
    int cnt = cntS; if (cnt > CAP) cnt = CAP;
    if (cnt > MAXNN) {
        // rare path: keep the 64 lexicographically-smallest (d2, idx) = stable top_k
        if (t == 0) {
            for (int s = 0; s < MAXNN; s++) {
                int best = s;
                for (int q = s + 1; q < cnt; q++) {
                    if (nD2[q] < nD2[best] || (nD2[q] == nD2[best] && nIdx[q] < nIdx[best])) best = q;
                }
                float td = nD2[best]; nD2[best] = nD2[s]; nD2[s] = td;
                int ti = nIdx[best]; nIdx[best] = nIdx[s]; nIdx[s] = ti;
            }
        }
        __syncthreads();
        cnt = MAXNN;
    }

    // influence weights (one thread per neighbor)
    if (t < cnt) {
        int n = nIdx[t];
        float rx = pb[n * 3 + 0] - cx, ry = pb[n * 3 + 1] - cy, rz = pb[n * 3 + 2] - cz;
#pragma unroll
        for (int k = 0; k < K_; k++) {
            float dx = rx - kp_pos[k * 3 + 0];
            float dy = ry - kp_pos[k * 3 + 1];
            float dz = rz - kp_pos[k * 3 + 2];
            float dist = sqrtf(dx * dx + dy * dy + dz * dz + 1e-12f);
            infl[t][k] = fmaxf(1.0f - dist / EXT, 0.0f);
        }
    }
    // stage gathered neighbor features
    for (int i = t; i < cnt * DM; i += 256) {
        int e = i >> 6, d = i & 63;
        xj[e][d] = xpre[((size_t)b * N_ + nIdx[e]) * DM + d];
    }
    __syncthreads();

    // s[k][d] = sum_e infl[e][k] * xj[e][d]
#pragma unroll
    for (int p = 0; p < 4; p++) {
        int pair = t + p * 256;
        int k = pair >> 6, d = pair & 63;
        float acc = 0.f;
        for (int e = 0; e < cnt; e++) acc = fmaf(infl[e][k], xj[e][d], acc);
        sS[pair] = acc;
    }
    __syncthreads();

    // feat[d'] = sum_{k,d} s[k][d] * kp_W[k][d][d']  (4-way k-split)
    {
        int dprime = t & 63, ks = t >> 6;
        float acc = 0.f;
        for (int k = ks * 4; k < ks * 4 + 4; k++) {
            const float* kw = kp_W + ((size_t)k * DM) * DM + dprime;
#pragma unroll
            for (int d = 0; d < DM; d++) acc = fmaf(sS[k * DM + d], kw[d * DM], acc);
        }
        featP[ks][dprime] = acc;
    }
    __syncthreads();
    if (t < DM) featP[0][t] = featP[0][t] + featP[1][t] + featP[2][t] + featP[3][t];
    if (t < CIN) xg[t] = x[((size_t)b * N_ + ctr) * CIN + t];
    __syncthreads();

    // out[o] = feat @ W_post + b_post + x[ctr] @ W_sc + b_sc
    {
        const int o = t;
        float acc = b_post[o] + b_sc[o];
#pragma unroll 8
        for (int d = 0; d < DM; d++) acc = fmaf(featP[0][d], W_post[d * COUT + o], acc);
#pragma unroll 8
        for (int c = 0; c < CIN; c++) acc = fmaf(xg[c], W_sc[c * COUT + o], acc);
        out_feat[((size_t)(b * M_ + m)) * COUT + o] = acc;
    }
}

extern "C" void kernel_launch(void* const* d_in, const int* in_sizes, int n_in,
                              void* d_out, int out_size, void* d_ws, size_t ws_size,
                              hipStream_t stream) {
    const float* x      = (const float*)d_in[0];
    const float* pos    = (const float*)d_in[1];
    const float* W_pre  = (const float*)d_in[2];
    const float* b_pre  = (const float*)d_in[3];
    const float* kp_pos = (const float*)d_in[4];
    const float* kp_W   = (const float*)d_in[5];
    const float* W_post = (const float*)d_in[6];
    const float* b_post = (const float*)d_in[7];
    const float* W_sc   = (const float*)d_in[8];
    const float* b_sc   = (const float*)d_in[9];

    float* out_feat = (float*)d_out;
    float* out_pos  = (float*)d_out + (size_t)B_ * M_ * COUT;

    int*   idxs = (int*)d_ws;
    float* xpre = (float*)((char*)d_ws + 64 * 1024);

    fps_pre_kernel<<<4 + (B_ * N_) / 32, 512, 0, stream>>>(pos, idxs, out_pos,
                                                           x, W_pre, b_pre, xpre);
    conv_kernel<<<B_ * M_, 256, 0, stream>>>(pos, x, xpre, idxs, kp_pos, kp_W,
                                             W_post, b_post, W_sc, b_sc, out_feat);
}

// Round 8
// 2491.000 us; speedup vs baseline: 1.2023x; 1.2023x over previous
//
#include <hip/hip_runtime.h>

#define B_    4
#define N_    8192
#define CIN   128
#define COUT  256
#define M_    2048
#define K_    16
#define DM    64
#define MAXNN 64
#define CAP   128
#define R2    0.01f
#define EXT   0.1f

typedef float v2f __attribute__((ext_vector_type(2)));

// Exact-rounded squared distance matching numpy's op order: (dx*dx + dy*dy) + dz*dz
__device__ __forceinline__ float d2_exact(float ax, float ay, float az,
                                          float bx, float by, float bz) {
    float dx = ax - bx, dy = ay - by, dz = az - bz;
    return __fadd_rn(__fadd_rn(__fmul_rn(dx, dx), __fmul_rn(dy, dy)), __fmul_rn(dz, dz));
}

// Packed distance update for one float2 pair of points, exact numpy rounding:
// d2 = ((dx*dx + dy*dy) + dz*dz). Subtraction done as p + (-c) with a pre-negated
// center (exact in IEEE). Plain VALU (no DPP) => no wait-state hazards.
// (verified correct + VGPR-pinning in round 7)
#define PAIR_UPD(JJ)                                                         \
    { v2f d2v, t0v, t1v;                                                     \
      asm("v_pk_add_f32 %0, %3, %6\n\t"                                      \
          "v_pk_add_f32 %1, %4, %7\n\t"                                      \
          "v_pk_add_f32 %2, %5, %8\n\t"                                      \
          "v_pk_mul_f32 %0, %0, %0\n\t"                                      \
          "v_pk_mul_f32 %1, %1, %1\n\t"                                      \
          "v_pk_mul_f32 %2, %2, %2\n\t"                                      \
          "v_pk_add_f32 %0, %0, %1\n\t"                                      \
          "v_pk_add_f32 %0, %0, %2"                                          \
          : "=&v"(d2v), "=&v"(t0v), "=&v"(t1v)                               \
          : "v"(px[JJ]), "v"(py[JJ]), "v"(pz[JJ]),                           \
            "v"(ncx2), "v"(ncy2), "v"(ncz2));                                \
      mnd[2*(JJ)]   = fminf(mnd[2*(JJ)],   d2v.x);                           \
      mnd[2*(JJ)+1] = fminf(mnd[2*(JJ)+1], d2v.y);                           \
      bv0 = fmaxf(bv0, mnd[2*(JJ)]);                                         \
      bv1 = fmaxf(bv1, mnd[2*(JJ)+1]); }

// u64-key max step via builtin DPP (compiler inserts the required VALU->DPP
// wait states; verified correct in rounds 4/5).
#define DPP_STEP2(CTRL)                                                                   \
    {                                                                                     \
        unsigned tlo = (unsigned)__builtin_amdgcn_update_dpp(0, (int)klo, CTRL, 0xF, 0xF, true); \
        unsigned thi = (unsigned)__builtin_amdgcn_update_dpp(0, (int)khi, CTRL, 0xF, 0xF, true); \
        unsigned long long tk = ((unsigned long long)thi << 32) | tlo;                    \
        unsigned long long ck = ((unsigned long long)khi << 32) | klo;                    \
        if (tk > ck) { klo = tlo; khi = thi; }                                            \
    }

// ---------------- K1 (merged): blocks 0..3 = FPS; blocks >=4 = pre-MLP ----------------
// FPS: 512 threads (8 waves), 16 pts/lane as 8 x float2 in asm-pinned VGPRs.
// Hot loop: packed-f32 distance update + value-only min/max. Post-loop: recover the
// lane-local first (smallest-n) index with a descending cndmask scan (no barrier).
// Key u64 = (d2_bits<<32) | ~n: u64 max == numpy argmax w/ first-index tie-break.
// 6 builtin-DPP steps -> lane63 -> atomicMax into 4-deep rotating LDS slot ->
// ONE barrier -> all read slot, load center from global (same-address, L1).
// Slot (m+2)&3 reset after the barrier => a full barrier lies between reset and reuse.
__global__ __launch_bounds__(512) void fps_pre_kernel(const float* __restrict__ pos,
                                                      int* __restrict__ idx_out,
                                                      float* __restrict__ out_pos,
                                                      const float* __restrict__ x,
                                                      const float* __restrict__ Wp,
                                                      const float* __restrict__ bvec,
                                                      float* __restrict__ xpre) {
    __shared__ union {
        unsigned long long keySlot[4];
        struct { float Ws[CIN * DM]; float xs[32][CIN]; } p;   // 48 KB
    } sh;

    const int t = threadIdx.x;

    if (blockIdx.x >= 4) {
        // ---------------- pre-MLP branch: 32 rows per block ----------------
        const size_t rowBase = (size_t)(blockIdx.x - 4) * 32;
        for (int i = t; i < CIN * DM; i += 512) sh.p.Ws[i] = Wp[i];
        for (int i = t; i < 32 * CIN; i += 512) {
            int r = i >> 7, c = i & 127;
            sh.p.xs[r][c] = x[(rowBase + r) * CIN + c];
        }
        __syncthreads();
        const int col = t & 63, r0 = t >> 6;   // r0 in [0,8)
        float acc[4];
        float bias = bvec[col];
#pragma unroll
        for (int rr = 0; rr < 4; rr++) acc[rr] = bias;
        for (int c = 0; c < CIN; c++) {
            float w = sh.p.Ws[c * DM + col];
#pragma unroll
            for (int rr = 0; rr < 4; rr++) acc[rr] = fmaf(sh.p.xs[r0 + 8 * rr][c], w, acc[rr]);
        }
#pragma unroll
        for (int rr = 0; rr < 4; rr++) xpre[(rowBase + r0 + 8 * rr) * DM + col] = acc[rr];
        return;
    }

    // ---------------- FPS branch ----------------
    const int b = blockIdx.x;
    const float* pb = pos + (size_t)b * N_ * 3;

    v2f px[8], py[8], pz[8];
    float mnd[16];
#pragma unroll
    for (int jj = 0; jj < 8; jj++) {
        int n0 = t + (2 * jj) * 512, n1 = n0 + 512;
        px[jj] = (v2f){pb[n0 * 3 + 0], pb[n1 * 3 + 0]};
        py[jj] = (v2f){pb[n0 * 3 + 1], pb[n1 * 3 + 1]};
        pz[jj] = (v2f){pb[n0 * 3 + 2], pb[n1 * 3 + 2]};
        mnd[2 * jj] = 1e30f; mnd[2 * jj + 1] = 1e30f;
    }
    float cx = pb[0], cy = pb[1], cz = pb[2];
    if (t < 4) sh.keySlot[t] = 0ull;
    if (t == 0) {
        idx_out[b * M_ + 0] = 0;
        float* op = out_pos + ((size_t)(b * M_ + 0)) * 3;
        op[0] = cx; op[1] = cy; op[2] = cz;
    }
    __syncthreads();

    for (int m = 1; m < M_; m++) {
        // exact sign-flip; p + (-c) is bit-identical to p - c
        const float ncx = -cx, ncy = -cy, ncz = -cz;
        const v2f ncx2 = (v2f){ncx, ncx}, ncy2 = (v2f){ncy, ncy}, ncz2 = (v2f){ncz, ncz};
        float bv0 = -1.0f, bv1 = -1.0f;
        PAIR_UPD(0) PAIR_UPD(1) PAIR_UPD(2) PAIR_UPD(3)
        PAIR_UPD(4) PAIR_UPD(5) PAIR_UPD(6) PAIR_UPD(7)
        const float lanemax = fmaxf(bv0, bv1);

        // recover lane-local first (smallest-n) index: descending scan, last writer wins
        unsigned bn = 0;
#pragma unroll
        for (int i = 15; i >= 0; i--) {
            if (mnd[i] == lanemax) bn = (unsigned)(t + i * 512);
        }

        unsigned klo = ~bn;
        unsigned khi = __float_as_uint(lanemax);
        // wave64 u64-key max-reduce via builtin DPP; winner lands in lane 63
        DPP_STEP2(0x111)  // row_shr:1
        DPP_STEP2(0x112)  // row_shr:2
        DPP_STEP2(0x114)  // row_shr:4
        DPP_STEP2(0x118)  // row_shr:8
        DPP_STEP2(0x142)  // row_bcast:15
        DPP_STEP2(0x143)  // row_bcast:31

        const int buf = m & 3;
        if ((t & 63) == 63) {
            atomicMax(&sh.keySlot[buf], ((unsigned long long)khi << 32) | klo);
        }
        __syncthreads();   // the single barrier
        const unsigned long long k0 = sh.keySlot[buf];
        if (t == 0) sh.keySlot[(m + 2) & 3] = 0ull;   // reused at m+2: barrier-ordered
        const unsigned widx = ~(unsigned)(k0 & 0xFFFFFFFFull);
        const float* cp = pb + (size_t)widx * 3;
        cx = cp[0]; cy = cp[1]; cz = cp[2];
        if (t == 0) {
            idx_out[b * M_ + m] = (int)widx;
            float* op = out_pos + ((size_t)(b * M_ + m)) * 3;
            op[0] = cx; op[1] = cy; op[2] = cz;
        }
    }
}

// ---------------- K3: fused neighbor search + KPConv + post + shortcut ----------------
__global__ __launch_bounds__(256) void conv_kernel(const float* __restrict__ pos,
                                                   const float* __restrict__ x,
                                                   const float* __restrict__ xpre,
                                                   const int* __restrict__ idxs,
                                                   const float* __restrict__ kp_pos,
                                                   const float* __restrict__ kp_W,
                                                   const float* __restrict__ W_post,
                                                   const float* __restrict__ b_post,
                                                   const float* __restrict__ W_sc,
                                                   const float* __restrict__ b_sc,
                                                   float* __restrict__ out_feat) {
    const int blk = blockIdx.x;
    const int b = blk / M_;
    const int m = blk % M_;
    const int t = threadIdx.x;

    __shared__ int   nIdx[CAP];
    __shared__ float nD2[CAP];
    __shared__ int   cntS;
    __shared__ float infl[MAXNN][K_];   // 4 KB
    __shared__ float xj[MAXNN][DM];     // 16 KB
    __shared__ float sS[K_ * DM];       // 4 KB
    __shared__ float featP[4][DM];      // 1 KB
    __shared__ float xg[CIN];           // 0.5 KB

    const float* pb = pos + (size_t)b * N_ * 3;
    const int ctr = idxs[b * M_ + m];
    const float cx = pb[ctr * 3 + 0], cy = pb[ctr * 3 + 1], cz = pb[ctr * 3 + 2];

    if (t == 0) cntS = 0;
    __syncthreads();

    // neighbor scan over all N points
    for (int j = 0; j < N_ / 256; j++) {
        int n = j * 256 + t;
        float x0 = pb[n * 3 + 0], y0 = pb[n * 3 + 1], z0 = pb[n * 3 + 2];
        float d = d2_exact(x0, y0, z0, cx, cy, cz);
        if (d <= R2) {
            int p = atomicAdd(&cntS, 1);
            if (p < CAP) { nIdx[p] = n; nD2[p] = d; }
        }
    }
    __syncthreads();
    int cnt = cntS; if (cnt > CAP) cnt = CAP;
    if (cnt > MAXNN) {
        // rare path: keep the 64 lexicographically-smallest (d2, idx) = stable top_k
        if (t == 0) {
            for (int s = 0; s < MAXNN; s++) {
                int best = s;
                for (int q = s + 1; q < cnt; q++) {
                    if (nD2[q] < nD2[best] || (nD2[q] == nD2[best] && nIdx[q] < nIdx[best])) best = q;
                }
                float td = nD2[best]; nD2[best] = nD2[s]; nD2[s] = td;
                int ti = nIdx[best]; nIdx[best] = nIdx[s]; nIdx[s] = ti;
            }
        }
        __syncthreads();
        cnt = MAXNN;
    }

    // influence weights (one thread per neighbor)
    if (t < cnt) {
        int n = nIdx[t];
        float rx = pb[n * 3 + 0] - cx, ry = pb[n * 3 + 1] - cy, rz = pb[n * 3 + 2] - cz;
#pragma unroll
        for (int k = 0; k < K_; k++) {
            float dx = rx - kp_pos[k * 3 + 0];
            float dy = ry - kp_pos[k * 3 + 1];
            float dz = rz - kp_pos[k * 3 + 2];
            float dist = sqrtf(dx * dx + dy * dy + dz * dz + 1e-12f);
            infl[t][k] = fmaxf(1.0f - dist / EXT, 0.0f);
        }
    }
    // stage gathered neighbor features
    for (int i = t; i < cnt * DM; i += 256) {
        int e = i >> 6, d = i & 63;
        xj[e][d] = xpre[((size_t)b * N_ + nIdx[e]) * DM + d];
    }
    __syncthreads();

    // s[k][d] = sum_e infl[e][k] * xj[e][d]
#pragma unroll
    for (int p = 0; p < 4; p++) {
        int pair = t + p * 256;
        int k = pair >> 6, d = pair & 63;
        float acc = 0.f;
        for (int e = 0; e < cnt; e++) acc = fmaf(infl[e][k], xj[e][d], acc);
        sS[pair] = acc;
    }
    __syncthreads();

    // feat[d'] = sum_{k,d} s[k][d] * kp_W[k][d][d']  (4-way k-split)
    {
        int dprime = t & 63, ks = t >> 6;
        float acc = 0.f;
        for (int k = ks * 4; k < ks * 4 + 4; k++) {
            const float* kw = kp_W + ((size_t)k * DM) * DM + dprime;
#pragma unroll
            for (int d = 0; d < DM; d++) acc = fmaf(sS[k * DM + d], kw[d * DM], acc);
        }
        featP[ks][dprime] = acc;
    }
    __syncthreads();
    if (t < DM) featP[0][t] = featP[0][t] + featP[1][t] + featP[2][t] + featP[3][t];
    if (t < CIN) xg[t] = x[((size_t)b * N_ + ctr) * CIN + t];
    __syncthreads();

    // out[o] = feat @ W_post + b_post + x[ctr] @ W_sc + b_sc
    {
        const int o = t;
        float acc = b_post[o] + b_sc[o];
#pragma unroll 8
        for (int d = 0; d < DM; d++) acc = fmaf(featP[0][d], W_post[d * COUT + o], acc);
#pragma unroll 8
        for (int c = 0; c < CIN; c++) acc = fmaf(xg[c], W_sc[c * COUT + o], acc);
        out_feat[((size_t)(b * M_ + m)) * COUT + o] = acc;
    }
}

extern "C" void kernel_launch(void* const* d_in, const int* in_sizes, int n_in,
                              void* d_out, int out_size, void* d_ws, size_t ws_size,
                              hipStream_t stream) {
    const float* x      = (const float*)d_in[0];
    const float* pos    = (const float*)d_in[1];
    const float* W_pre  = (const float*)d_in[2];
    const float* b_pre  = (const float*)d_in[3];
    const float* kp_pos = (const float*)d_in[4];
    const float* kp_W   = (const float*)d_in[5];
    const float* W_post = (const float*)d_in[6];
    const float* b_post = (const float*)d_in[7];
    const float* W_sc   = (const float*)d_in[8];
    const float* b_sc   = (const float*)d_in[9];

    float* out_feat = (float*)d_out;
    float* out_pos  = (float*)d_out + (size_t)B_ * M_ * COUT;

    int*   idxs = (int*)d_ws;
    float* xpre = (float*)((char*)d_ws + 64 * 1024);

    fps_pre_kernel<<<4 + (B_ * N_) / 32, 512, 0, stream>>>(pos, idxs, out_pos,
                                                           x, W_pre, b_pre, xpre);
    conv_kernel<<<B_ * M_, 256, 0, stream>>>(pos, x, xpre, idxs, kp_pos, kp_W,
                                             W_post, b_post, W_sc, b_sc, out_feat);
}

// Round 9
// 2395.930 us; speedup vs baseline: 1.2500x; 1.0397x over previous
//
#include <hip/hip_runtime.h>

#define B_    4
#define N_    8192
#define CIN   128
#define COUT  256
#define M_    2048
#define K_    16
#define DM    64
#define MAXNN 64
#define CAP   128
#define R2    0.01f
#define EXT   0.1f

typedef float v2f __attribute__((ext_vector_type(2)));

// Exact-rounded squared distance matching numpy's op order: (dx*dx + dy*dy) + dz*dz
__device__ __forceinline__ float d2_exact(float ax, float ay, float az,
                                          float bx, float by, float bz) {
    float dx = ax - bx, dy = ay - by, dz = az - bz;
    return __fadd_rn(__fadd_rn(__fmul_rn(dx, dx), __fmul_rn(dy, dy)), __fmul_rn(dz, dz));
}

// u64-key max step via builtin DPP (compiler inserts the required VALU->DPP
// wait states; verified correct rounds 4/5/8).
#define DPP_STEP2(CTRL)                                                                   \
    {                                                                                     \
        unsigned tlo = (unsigned)__builtin_amdgcn_update_dpp(0, (int)klo, CTRL, 0xF, 0xF, true); \
        unsigned thi = (unsigned)__builtin_amdgcn_update_dpp(0, (int)khi, CTRL, 0xF, 0xF, true); \
        unsigned long long tk = ((unsigned long long)thi << 32) | tlo;                    \
        unsigned long long ck = ((unsigned long long)khi << 32) | klo;                    \
        if (tk > ck) { klo = tlo; khi = thi; }                                            \
    }

// ---------------- K1 (merged): blocks 0..3 = FPS; blocks >=4 = pre-MLP ----------------
// FPS: 1024 threads (16 waves), 8 pts/lane as 4 x float2 => only ~32 data VGPRs, which
// fits the 4-wave/EU 128-reg budget WITHOUT AGPR banking (the ~600 cyc/SIMD tax measured
// in rounds 5-8 at 512thr/16pt). C-code v2f update (contract off => exact numpy
// rounding), in-loop slot tracking, u64 key (d2_bits<<32)|~n, 6 builtin-DPP steps,
// lane63 atomicMax into 4-deep rotating LDS slot, ONE barrier. idx goes to an LDS
// buffer in-loop (no global stores in the loop); idx_out and out_pos are written
// after the loop by all threads.
__global__ __launch_bounds__(1024) void fps_pre_kernel(const float* __restrict__ pos,
                                                       int* __restrict__ idx_out,
                                                       float* __restrict__ out_pos,
                                                       const float* __restrict__ x,
                                                       const float* __restrict__ Wp,
                                                       const float* __restrict__ bvec,
                                                       float* __restrict__ xpre) {
    __shared__ union {
        struct { unsigned long long keySlot[4]; int idxb[M_]; } f;     // ~8 KB
        struct { float Ws[CIN * DM]; float xs[32][CIN]; } p;           // 48 KB
    } sh;

    const int t = threadIdx.x;

    if (blockIdx.x >= 4) {
        // ---------------- pre-MLP branch: 32 rows per block, 1024 threads ----------------
        const size_t rowBase = (size_t)(blockIdx.x - 4) * 32;
        for (int i = t; i < CIN * DM; i += 1024) sh.p.Ws[i] = Wp[i];
        for (int i = t; i < 32 * CIN; i += 1024) {
            int r = i >> 7, c = i & 127;
            sh.p.xs[r][c] = x[(rowBase + r) * CIN + c];
        }
        __syncthreads();
        const int col = t & 63, r0 = t >> 6;   // r0 in [0,16)
        float acc[2];
        float bias = bvec[col];
        acc[0] = bias; acc[1] = bias;
        for (int c = 0; c < CIN; c++) {
            float w = sh.p.Ws[c * DM + col];
            acc[0] = fmaf(sh.p.xs[r0][c], w, acc[0]);
            acc[1] = fmaf(sh.p.xs[r0 + 16][c], w, acc[1]);
        }
        xpre[(rowBase + r0) * DM + col] = acc[0];
        xpre[(rowBase + r0 + 16) * DM + col] = acc[1];
        return;
    }

    // ---------------- FPS branch ----------------
    const int b = blockIdx.x;
    const float* pb = pos + (size_t)b * N_ * 3;

    v2f px[4], py[4], pz[4];
    float mnd[8];
#pragma unroll
    for (int jj = 0; jj < 4; jj++) {
        int n0 = t + (2 * jj) * 1024, n1 = n0 + 1024;
        px[jj] = (v2f){pb[n0 * 3 + 0], pb[n1 * 3 + 0]};
        py[jj] = (v2f){pb[n0 * 3 + 1], pb[n1 * 3 + 1]};
        pz[jj] = (v2f){pb[n0 * 3 + 2], pb[n1 * 3 + 2]};
        mnd[2 * jj] = 1e30f; mnd[2 * jj + 1] = 1e30f;
    }
    float cx = pb[0], cy = pb[1], cz = pb[2];
    if (t < 4) sh.f.keySlot[t] = 0ull;
    if (t == 0) sh.f.idxb[0] = 0;
    __syncthreads();

    for (int m = 1; m < M_; m++) {
        // fused mind-update + lane-local argmax; ascending slot => ascending global idx,
        // strict > keeps the first max => smallest index on ties. contract(off) => the
        // element-wise rounding matches numpy exactly.
        float bv = -1.0f; int bj = 0;
        {
#pragma clang fp contract(off)
            const v2f cx2 = (v2f){cx, cx}, cy2 = (v2f){cy, cy}, cz2 = (v2f){cz, cz};
#pragma unroll
            for (int jj = 0; jj < 4; jj++) {
                v2f dx = px[jj] - cx2, dy = py[jj] - cy2, dz = pz[jj] - cz2;
                v2f d = (dx * dx + dy * dy) + dz * dz;
                float n0 = fminf(mnd[2 * jj], d.x);
                float n1 = fminf(mnd[2 * jj + 1], d.y);
                mnd[2 * jj] = n0; mnd[2 * jj + 1] = n1;
                if (n0 > bv) { bv = n0; bj = 2 * jj; }
                if (n1 > bv) { bv = n1; bj = 2 * jj + 1; }
            }
        }
        const unsigned bn = (unsigned)(t + (bj << 10));
        unsigned klo = ~bn;
        unsigned khi = __float_as_uint(bv);

        // wave64 u64-key max-reduce via builtin DPP; winner lands in lane 63
        DPP_STEP2(0x111)  // row_shr:1
        DPP_STEP2(0x112)  // row_shr:2
        DPP_STEP2(0x114)  // row_shr:4
        DPP_STEP2(0x118)  // row_shr:8
        DPP_STEP2(0x142)  // row_bcast:15
        DPP_STEP2(0x143)  // row_bcast:31

        const int buf = m & 3;
        if ((t & 63) == 63) {
            atomicMax(&sh.f.keySlot[buf], ((unsigned long long)khi << 32) | klo);
        }
        __syncthreads();   // the single barrier
        const unsigned long long k0 = sh.f.keySlot[buf];
        if (t == 0) {
            sh.f.keySlot[(m + 2) & 3] = 0ull;   // reused at m+2: barrier-ordered
        }
        const unsigned widx = ~(unsigned)(k0 & 0xFFFFFFFFull);
        if (t == 0) sh.f.idxb[m] = (int)widx;
        const float* cp = pb + (size_t)widx * 3;
        cx = cp[0]; cy = cp[1]; cz = cp[2];
    }
    __syncthreads();

    // post-loop writeback: idx + gathered centers (off the critical chain)
    for (int m = t; m < M_; m += 1024) {
        int n = sh.f.idxb[m];
        idx_out[b * M_ + m] = n;
        float* op = out_pos + ((size_t)(b * M_ + m)) * 3;
        const float* sp = pb + (size_t)n * 3;
        op[0] = sp[0]; op[1] = sp[1]; op[2] = sp[2];
    }
}

// ---------------- K3: fused neighbor search + KPConv + post + shortcut ----------------
__global__ __launch_bounds__(256) void conv_kernel(const float* __restrict__ pos,
                                                   const float* __restrict__ x,
                                                   const float* __restrict__ xpre,
                                                   const int* __restrict__ idxs,
                                                   const float* __restrict__ kp_pos,
                                                   const float* __restrict__ kp_W,
                                                   const float* __restrict__ W_post,
                                                   const float* __restrict__ b_post,
                                                   const float* __restrict__ W_sc,
                                                   const float* __restrict__ b_sc,
                                                   float* __restrict__ out_feat) {
    const int blk = blockIdx.x;
    const int b = blk / M_;
    const int m = blk % M_;
    const int t = threadIdx.x;

    __shared__ int   nIdx[CAP];
    __shared__ float nD2[CAP];
    __shared__ int   cntS;
    __shared__ float infl[MAXNN][K_];   // 4 KB
    __shared__ float xj[MAXNN][DM];     // 16 KB
    __shared__ float sS[K_ * DM];       // 4 KB
    __shared__ float featP[4][DM];      // 1 KB
    __shared__ float xg[CIN];           // 0.5 KB

    const float* pb = pos + (size_t)b * N_ * 3;
    const int ctr = idxs[b * M_ + m];
    const float cx = pb[ctr * 3 + 0], cy = pb[ctr * 3 + 1], cz = pb[ctr * 3 + 2];

    if (t == 0) cntS = 0;
    __syncthreads();

    // neighbor scan over all N points
    for (int j = 0; j < N_ / 256; j++) {
        int n = j * 256 + t;
        float x0 = pb[n * 3 + 0], y0 = pb[n * 3 + 1], z0 = pb[n * 3 + 2];
        float d = d2_exact(x0, y0, z0, cx, cy, cz);
        if (d <= R2) {
            int p = atomicAdd(&cntS, 1);
            if (p < CAP) { nIdx[p] = n; nD2[p] = d; }
        }
    }
    __syncthreads();
    int cnt = cntS; if (cnt > CAP) cnt = CAP;
    if (cnt > MAXNN) {
        // rare path: keep the 64 lexicographically-smallest (d2, idx) = stable top_k
        if (t == 0) {
            for (int s = 0; s < MAXNN; s++) {
                int best = s;
                for (int q = s + 1; q < cnt; q++) {
                    if (nD2[q] < nD2[best] || (nD2[q] == nD2[best] && nIdx[q] < nIdx[best])) best = q;
                }
                float td = nD2[best]; nD2[best] = nD2[s]; nD2[s] = td;
                int ti = nIdx[best]; nIdx[best] = nIdx[s]; nIdx[s] = ti;
            }
        }
        __syncthreads();
        cnt = MAXNN;
    }

    // influence weights (one thread per neighbor)
    if (t < cnt) {
        int n = nIdx[t];
        float rx = pb[n * 3 + 0] - cx, ry = pb[n * 3 + 1] - cy, rz = pb[n * 3 + 2] - cz;
#pragma unroll
        for (int k = 0; k < K_; k++) {
            float dx = rx - kp_pos[k * 3 + 0];
            float dy = ry - kp_pos[k * 3 + 1];
            float dz = rz - kp_pos[k * 3 + 2];
            float dist = sqrtf(dx * dx + dy * dy + dz * dz + 1e-12f);
            infl[t][k] = fmaxf(1.0f - dist / EXT, 0.0f);
        }
    }
    // stage gathered neighbor features
    for (int i = t; i < cnt * DM; i += 256) {
        int e = i >> 6, d = i & 63;
        xj[e][d] = xpre[((size_t)b * N_ + nIdx[e]) * DM + d];
    }
    __syncthreads();

    // s[k][d] = sum_e infl[e][k] * xj[e][d]
#pragma unroll
    for (int p = 0; p < 4; p++) {
        int pair = t + p * 256;
        int k = pair >> 6, d = pair & 63;
        float acc = 0.f;
        for (int e = 0; e < cnt; e++) acc = fmaf(infl[e][k], xj[e][d], acc);
        sS[pair] = acc;
    }
    __syncthreads();

    // feat[d'] = sum_{k,d} s[k][d] * kp_W[k][d][d']  (4-way k-split)
    {
        int dprime = t & 63, ks = t >> 6;
        float acc = 0.f;
        for (int k = ks * 4; k < ks * 4 + 4; k++) {
            const float* kw = kp_W + ((size_t)k * DM) * DM + dprime;
#pragma unroll
            for (int d = 0; d < DM; d++) acc = fmaf(sS[k * DM + d], kw[d * DM], acc);
        }
        featP[ks][dprime] = acc;
    }
    __syncthreads();
    if (t < DM) featP[0][t] = featP[0][t] + featP[1][t] + featP[2][t] + featP[3][t];
    if (t < CIN) xg[t] = x[((size_t)b * N_ + ctr) * CIN + t];
    __syncthreads();

    // out[o] = feat @ W_post + b_post + x[ctr] @ W_sc + b_sc
    {
        const int o = t;
        float acc = b_post[o] + b_sc[o];
#pragma unroll 8
        for (int d = 0; d < DM; d++) acc = fmaf(featP[0][d], W_post[d * COUT + o], acc);
#pragma unroll 8
        for (int c = 0; c < CIN; c++) acc = fmaf(xg[c], W_sc[c * COUT + o], acc);
        out_feat[((size_t)(b * M_ + m)) * COUT + o] = acc;
    }
}

extern "C" void kernel_launch(void* const* d_in, const int* in_sizes, int n_in,
                              void* d_out, int out_size, void* d_ws, size_t ws_size,
                              hipStream_t stream) {
    const float* x      = (const float*)d_in[0];
    const float* pos    = (const float*)d_in[1];
    const float* W_pre  = (const float*)d_in[2];
    const float* b_pre  = (const float*)d_in[3];
    const float* kp_pos = (const float*)d_in[4];
    const float* kp_W   = (const float*)d_in[5];
    const float* W_post = (const float*)d_in[6];
    const float* b_post = (const float*)d_in[7];
    const float* W_sc   = (const float*)d_in[8];
    const float* b_sc   = (const float*)d_in[9];

    float* out_feat = (float*)d_out;
    float* out_pos  = (float*)d_out + (size_t)B_ * M_ * COUT;

    int*   idxs = (int*)d_ws;
    float* xpre = (float*)((char*)d_ws + 64 * 1024);

    fps_pre_kernel<<<4 + (B_ * N_) / 32, 1024, 0, stream>>>(pos, idxs, out_pos,
                                                            x, W_pre, b_pre, xpre);
    conv_kernel<<<B_ * M_, 256, 0, stream>>>(pos, x, xpre, idxs, kp_pos, kp_W,
                                             W_post, b_post, W_sc, b_sc, out_feat);
}